// Round 10
// baseline (631.789 us; speedup 1.0000x reference)
//
#include <hip/hip_runtime.h>
#include <hip/hip_cooperative_groups.h>
#include <hip/hip_bf16.h>
#include <math.h>

namespace cg = cooperative_groups;

#define N_NODES 50000
#define N_EDGES 640000
#define HEADS 4
#define CDIM 32
#define HC 128          // HEADS*CDIM
#define DIN 128
#define DOUT 32
#define NEG_SLOPE 0.2f
#define TPAD 136        // 128 + 8 bf16 pad -> 2-way bank aliasing (free)
#define SCAN_B 256
#define SCAN_NB ((N_NODES + SCAN_B - 1) / SCAN_B)   // 196
#define CSR_BLOCKS 1024 // <=4 blocks/CU, guaranteed co-resident for grid.sync

typedef __hip_bfloat16 bf16;
typedef __attribute__((ext_vector_type(8))) short short8;
typedef __attribute__((ext_vector_type(4))) float floatx4;

static __device__ __forceinline__ float bflo(unsigned w) { return __uint_as_float(w << 16); }
static __device__ __forceinline__ float bfhi(unsigned w) { return __uint_as_float(w & 0xFFFF0000u); }
static __device__ __forceinline__ unsigned short f2bf(float f) {
    union { bf16 h; unsigned short u; } cv; cv.h = __float2bfloat16(f); return cv.u;
}

// Cooperative CSR builder: zero deg + cvec | count | scan (2 phases) | fill.
// Replaces 5 small dispatches with one launch; phases separated by grid.sync().
__global__ __launch_bounds__(256) void k_csr(
    const int* __restrict__ ei, unsigned* __restrict__ deg,
    unsigned* __restrict__ offs, unsigned* __restrict__ bsum,
    int* __restrict__ srcs,
    const float* __restrict__ bias, const float* __restrict__ Wp,
    const float* __restrict__ bp, float* __restrict__ cvec)
{
    cg::grid_group grid = cg::this_grid();
    __shared__ unsigned sh[SCAN_B];
    const int t = threadIdx.x, b = blockIdx.x;
    const int gsz = CSR_BLOCKS * 256, gid = b * 256 + t;

    // phase 0: zero deg; cvec = bias @ Wp + bp
    for (int i = gid; i < N_NODES; i += gsz) deg[i] = 0u;
    if (gid < DOUT) {
        float v = bp[gid];
        for (int c = 0; c < HC; c++) v += bias[c] * Wp[c * DOUT + gid];
        cvec[gid] = v;
    }
    grid.sync();

    // phase 1: in-degree count
    for (int e = gid; e < N_EDGES; e += gsz)
        atomicAdd(&deg[ei[N_EDGES + e]], 1u);
    grid.sync();

    // phase 2a: block-local exclusive scan (blocks 0..SCAN_NB-1)
    if (b < SCAN_NB) {
        const int i = b * SCAN_B + t;
        const unsigned d = (i < N_NODES) ? deg[i] : 0u;
        sh[t] = d;
        __syncthreads();
        for (int off = 1; off < SCAN_B; off <<= 1) {
            unsigned v = (t >= off) ? sh[t - off] : 0u;
            __syncthreads();
            sh[t] += v;
            __syncthreads();
        }
        if (i < N_NODES) offs[i] = sh[t] - d;
        if (t == SCAN_B - 1) bsum[b] = sh[t];
    }
    grid.sync();

    // phase 2b: add block bases; write final offs + cursor (in deg)
    if (b < SCAN_NB) {
        sh[t] = (t < SCAN_NB && t < b) ? bsum[t] : 0u;
        __syncthreads();
        for (int off = SCAN_B / 2; off > 0; off >>= 1) {
            if (t < off) sh[t] += sh[t + off];
            __syncthreads();
        }
        const unsigned base = sh[0];
        const int i = b * SCAN_B + t;
        if (i < N_NODES) {
            const unsigned v = offs[i] + base;
            offs[i] = v;
            deg[i] = v;                     // cursor init
        }
        if (i == 0) offs[N_NODES] = N_EDGES;
    }
    grid.sync();

    // phase 3: bucket src ids by dst
    for (int e = gid; e < N_EDGES; e += gsz) {
        const int dst = ei[N_EDGES + e];
        const unsigned pos = atomicAdd(&deg[dst], 1u);
        srcs[pos] = ei[e];
    }
}

// Phase 1: xl = x@Wl then xr = x@Wr in ONE pass over x (staged once).
// W staged directly from f32 global with inline bf16 cvt (W is L2-resident).
__global__ __launch_bounds__(256) void k_transform(
    const float* __restrict__ x,
    const float* __restrict__ Wl,
    const float* __restrict__ Wr,
    bf16* __restrict__ xl, bf16* __restrict__ xr)
{
    __shared__ __align__(16) unsigned short xs[64][TPAD];
    __shared__ __align__(16) unsigned short Ws[128][TPAD];
    const int t = threadIdx.x;
    const int n0 = blockIdx.x * 64;

    for (int i = t; i < 64 * DIN / 4; i += 256) {
        const int n = i >> 5, c4 = (i & 31) * 4;
        float4 v = make_float4(0.f, 0.f, 0.f, 0.f);
        if (n0 + n < N_NODES)
            v = *(const float4*)(x + (size_t)(n0 + n) * DIN + c4);
        xs[n][c4]     = f2bf(v.x);
        xs[n][c4 + 1] = f2bf(v.y);
        xs[n][c4 + 2] = f2bf(v.z);
        xs[n][c4 + 3] = f2bf(v.w);
    }
    for (int i = t; i < DIN * HC / 4; i += 256) {   // W[c][j], stage W^T
        const float4 wv = ((const float4*)Wl)[i];
        const int c = i >> 5, j = (i & 31) * 4;
        Ws[j][c]     = f2bf(wv.x);
        Ws[j + 1][c] = f2bf(wv.y);
        Ws[j + 2][c] = f2bf(wv.z);
        Ws[j + 3][c] = f2bf(wv.w);
    }
    __syncthreads();

    const int w = t >> 6, lane = t & 63;
    const int m = lane & 15, quad = lane >> 4;

    short8 af[4];
    #pragma unroll
    for (int kk = 0; kk < 4; kk++)
        af[kk] = *(const short8*)&xs[w * 16 + m][kk * 32 + quad * 8];

    #pragma unroll
    for (int jt = 0; jt < 8; jt++) {
        floatx4 acc = {0.f, 0.f, 0.f, 0.f};
        #pragma unroll
        for (int kk = 0; kk < 4; kk++) {
            short8 bfr = *(const short8*)&Ws[jt * 16 + m][kk * 32 + quad * 8];
            acc = __builtin_amdgcn_mfma_f32_16x16x32_bf16(af[kk], bfr, acc, 0, 0, 0);
        }
        #pragma unroll
        for (int r = 0; r < 4; r++) {               // C/D: col=m, row=quad*4+r
            int n = n0 + w * 16 + quad * 4 + r;
            if (n < N_NODES)
                xl[(size_t)n * HC + jt * 16 + m] = __float2bfloat16(acc[r]);
        }
    }
    __syncthreads();                                // all waves done with Ws

    for (int i = t; i < DIN * HC / 4; i += 256) {
        const float4 wv = ((const float4*)Wr)[i];
        const int c = i >> 5, j = (i & 31) * 4;
        Ws[j][c]     = f2bf(wv.x);
        Ws[j + 1][c] = f2bf(wv.y);
        Ws[j + 2][c] = f2bf(wv.z);
        Ws[j + 3][c] = f2bf(wv.w);
    }
    __syncthreads();

    #pragma unroll
    for (int jt = 0; jt < 8; jt++) {
        floatx4 acc = {0.f, 0.f, 0.f, 0.f};
        #pragma unroll
        for (int kk = 0; kk < 4; kk++) {
            short8 bfr = *(const short8*)&Ws[jt * 16 + m][kk * 32 + quad * 8];
            acc = __builtin_amdgcn_mfma_f32_16x16x32_bf16(af[kk], bfr, acc, 0, 0, 0);
        }
        #pragma unroll
        for (int r = 0; r < 4; r++) {
            int n = n0 + w * 16 + quad * 4 + r;
            if (n < N_NODES)
                xr[(size_t)n * HC + jt * 16 + m] = __float2bfloat16(acc[r]);
        }
    }
}

// Fused logit + exp + aggregate + projection. One wave per node.
// Lane = (es = lane>>4, hq = lane&15): 4 edge slots x 16 lanes; lane owns
// cols 8hq..8hq+7 (one uint4 of the 256B row; head = hq>>2). Head-dot
// reduce = 2 shuffles (over the 4-lane cq group). 4 independent row loads
// in flight. All register arrays use unrolled constant indices.
__global__ __launch_bounds__(256) void k_agg(
    const int* __restrict__ srcs, const unsigned* __restrict__ offs,
    const unsigned* __restrict__ xl2,   // bf16 xl as uint pairs [N][64]
    const unsigned* __restrict__ xr2,   // bf16 xr as uint pairs [N][64]
    const float* __restrict__ att,
    const float* __restrict__ Wp, const float* __restrict__ cvec,
    float* __restrict__ out)
{
    __shared__ float sWp[HC][DOUT];     // 16 KB
    __shared__ float srow[4][HC];
    const int t = threadIdx.x;
    for (int i = t; i < HC * DOUT; i += 256)
        ((float*)sWp)[i] = Wp[i];
    __syncthreads();

    const int w = t >> 6, lane = t & 63;
    const int node = blockIdx.x * 4 + w;
    const int es = lane >> 4, hq = lane & 15;
    const int c0 = hq * 8;

    const uint4 xru = ((const uint4*)(xr2 + (size_t)node * 64))[hq];
    float xr_[8];
    xr_[0] = bflo(xru.x); xr_[1] = bfhi(xru.x);
    xr_[2] = bflo(xru.y); xr_[3] = bfhi(xru.y);
    xr_[4] = bflo(xru.z); xr_[5] = bfhi(xru.z);
    xr_[6] = bflo(xru.w); xr_[7] = bfhi(xru.w);
    const float4 av0 = ((const float4*)att)[hq * 2];
    const float4 av1 = ((const float4*)att)[hq * 2 + 1];
    float a_[8] = {av0.x, av0.y, av0.z, av0.w, av1.x, av1.y, av1.z, av1.w};

    const unsigned lo = offs[node], hi = offs[node + 1];
    float s_run = 0.f;
    float acc[8] = {0.f, 0.f, 0.f, 0.f, 0.f, 0.f, 0.f, 0.f};

    for (unsigned base = lo; base < hi; base += 64) {
        const unsigned j = base + lane;
        const int srcj = (j < hi) ? srcs[j] : 0;
        const int cnt = (int)((hi - base < 64u) ? (hi - base) : 64u);
        int sj = __shfl(srcj, es, 64);
        uint4 xw = ((const uint4*)(xl2 + ((size_t)((es < cnt) ? sj : 0) << 6)))[hq];
        for (int i = 0; i < cnt; i += 4) {
            const uint4 cur = xw;
            const int eidx = i + es;
            const int ii = eidx + 4;                // next edge for my slot
            sj = __shfl(srcj, ii & 63, 64);
            xw = ((const uint4*)(xl2 + ((size_t)((ii < cnt) ? sj : 0) << 6)))[hq];

            float x_[8];
            x_[0] = bflo(cur.x); x_[1] = bfhi(cur.x);
            x_[2] = bflo(cur.y); x_[3] = bfhi(cur.y);
            x_[4] = bflo(cur.z); x_[5] = bfhi(cur.z);
            x_[6] = bflo(cur.w); x_[7] = bfhi(cur.w);
            float p = 0.f;
            #pragma unroll
            for (int k = 0; k < 8; k++) {
                float v = x_[k] + xr_[k];
                v = fmaxf(v, NEG_SLOPE * v);
                p = fmaf(a_[k], v, p);
            }
            p += __shfl_xor(p, 1, 64);
            p += __shfl_xor(p, 2, 64);              // logit(edge eidx, head hq>>2)
            const float e_ = (eidx < cnt) ? __expf(p) : 0.f;
            s_run += e_;
            #pragma unroll
            for (int k = 0; k < 8; k++) acc[k] = fmaf(x_[k], e_, acc[k]);
        }
    }
    // combine the 4 edge slots (lanes differing in bits 4,5; same cols)
    s_run += __shfl_xor(s_run, 16, 64);
    s_run += __shfl_xor(s_run, 32, 64);
    #pragma unroll
    for (int k = 0; k < 8; k++) {
        acc[k] += __shfl_xor(acc[k], 16, 64);
        acc[k] += __shfl_xor(acc[k], 32, 64);
    }
    const float rden = 1.f / (s_run + 1e-16f);

    if (es == 0) {
        float4 r0 = {acc[0] * rden, acc[1] * rden, acc[2] * rden, acc[3] * rden};
        float4 r1 = {acc[4] * rden, acc[5] * rden, acc[6] * rden, acc[7] * rden};
        *(float4*)&srow[w][c0]     = r0;
        *(float4*)&srow[w][c0 + 4] = r1;
    }
    // same-wave LDS RAW: in-order DS pipe, no barrier needed
    const int jj = lane & 31, half = lane >> 5;
    float pacc = 0.f;
    const int cb = half * 64;
    #pragma unroll 8
    for (int c = 0; c < 64; c++)
        pacc += srow[w][cb + c] * sWp[cb + c][jj];
    pacc += __shfl_down(pacc, 32, 64);
    if (lane < 32)
        out[(size_t)node * DOUT + jj] = pacc + cvec[jj];
}

extern "C" void kernel_launch(void* const* d_in, const int* in_sizes, int n_in,
                              void* d_out, int out_size, void* d_ws, size_t ws_size,
                              hipStream_t stream)
{
    const float* x    = (const float*)d_in[0];
    const int*   ei   = (const int*)d_in[1];
    const float* Wl   = (const float*)d_in[2];
    const float* Wr   = (const float*)d_in[3];
    const float* att  = (const float*)d_in[4];
    const float* bias = (const float*)d_in[5];
    const float* Wp   = (const float*)d_in[6];
    const float* bp   = (const float*)d_in[7];
    float* out = (float*)d_out;

    // workspace (~28.4 MB):
    // xl bf16[N*HC] | xr bf16[N*HC] | cvec f32[32] | deg/cursor u32[N]
    // | offs u32[N+1] | bsum u32[256] | srcs i32[E]
    bf16* xl       = (bf16*)d_ws;
    bf16* xr       = xl + (size_t)N_NODES * HC;
    float* cvec    = (float*)(xr + (size_t)N_NODES * HC);
    unsigned* deg  = (unsigned*)(cvec + DOUT);
    unsigned* offs = deg + N_NODES;
    unsigned* bsum = offs + (N_NODES + 1);
    int* srcs      = (int*)(bsum + 256);

    void* csr_args[] = { (void*)&ei, (void*)&deg, (void*)&offs, (void*)&bsum,
                         (void*)&srcs, (void*)&bias, (void*)&Wp, (void*)&bp,
                         (void*)&cvec };
    hipLaunchCooperativeKernel((void*)k_csr, dim3(CSR_BLOCKS), dim3(256),
                               csr_args, 0, stream);
    k_transform<<<(N_NODES + 63) / 64, 256, 0, stream>>>(x, Wl, Wr, xl, xr);
    k_agg<<<N_NODES / 4, 256, 0, stream>>>(srcs, offs,
        (const unsigned*)xl, (const unsigned*)xr, att, Wp, cvec, out);
}

// Round 11
// 246.073 us; speedup vs baseline: 2.5675x; 2.5675x over previous
//
#include <hip/hip_runtime.h>
#include <hip/hip_bf16.h>
#include <math.h>

#define N_NODES 50000
#define N_EDGES 640000
#define HEADS 4
#define CDIM 32
#define HC 128          // HEADS*CDIM
#define DIN 128
#define DOUT 32
#define NEG_SLOPE 0.2f
#define TPAD 136        // 128 + 8 bf16 pad -> 2-way bank aliasing (free)
#define SCAN_B 256
#define SCAN_NB ((N_NODES + SCAN_B - 1) / SCAN_B)   // 196
#define TF_NB ((N_NODES + 63) / 64)                 // 782

typedef __hip_bfloat16 bf16;
typedef __attribute__((ext_vector_type(8))) short short8;
typedef __attribute__((ext_vector_type(4))) float floatx4;

static __device__ __forceinline__ float bflo(unsigned w) { return __uint_as_float(w << 16); }
static __device__ __forceinline__ float bfhi(unsigned w) { return __uint_as_float(w & 0xFFFF0000u); }
static __device__ __forceinline__ unsigned short f2bf(float f) {
    union { bf16 h; unsigned short u; } cv; cv.h = __float2bfloat16(f); return cv.u;
}

// Phase 1: xl = x@Wl then xr = x@Wr in ONE pass over x (staged once).
// Side job: zero deg[] (runs before k_count in stream order — no memset).
__global__ __launch_bounds__(256) void k_transform(
    const float* __restrict__ x,
    const float* __restrict__ Wl,
    const float* __restrict__ Wr,
    bf16* __restrict__ xl, bf16* __restrict__ xr,
    unsigned* __restrict__ deg)
{
    __shared__ __align__(16) unsigned short xs[64][TPAD];
    __shared__ __align__(16) unsigned short Ws[128][TPAD];
    const int t = threadIdx.x;
    const int n0 = blockIdx.x * 64;

    // zero my slice of deg (64 entries/block covers N_NODES)
    if (t < 64) {
        const int i = blockIdx.x * 64 + t;
        if (i < N_NODES) deg[i] = 0u;
    }

    for (int i = t; i < 64 * DIN / 4; i += 256) {
        const int n = i >> 5, c4 = (i & 31) * 4;
        float4 v = make_float4(0.f, 0.f, 0.f, 0.f);
        if (n0 + n < N_NODES)
            v = *(const float4*)(x + (size_t)(n0 + n) * DIN + c4);
        xs[n][c4]     = f2bf(v.x);
        xs[n][c4 + 1] = f2bf(v.y);
        xs[n][c4 + 2] = f2bf(v.z);
        xs[n][c4 + 3] = f2bf(v.w);
    }
    for (int i = t; i < DIN * HC / 4; i += 256) {   // W[c][j], stage W^T
        const float4 wv = ((const float4*)Wl)[i];
        const int c = i >> 5, j = (i & 31) * 4;
        Ws[j][c]     = f2bf(wv.x);
        Ws[j + 1][c] = f2bf(wv.y);
        Ws[j + 2][c] = f2bf(wv.z);
        Ws[j + 3][c] = f2bf(wv.w);
    }
    __syncthreads();

    const int w = t >> 6, lane = t & 63;
    const int m = lane & 15, quad = lane >> 4;

    short8 af[4];
    #pragma unroll
    for (int kk = 0; kk < 4; kk++)
        af[kk] = *(const short8*)&xs[w * 16 + m][kk * 32 + quad * 8];

    #pragma unroll
    for (int jt = 0; jt < 8; jt++) {
        floatx4 acc = {0.f, 0.f, 0.f, 0.f};
        #pragma unroll
        for (int kk = 0; kk < 4; kk++) {
            short8 bfr = *(const short8*)&Ws[jt * 16 + m][kk * 32 + quad * 8];
            acc = __builtin_amdgcn_mfma_f32_16x16x32_bf16(af[kk], bfr, acc, 0, 0, 0);
        }
        #pragma unroll
        for (int r = 0; r < 4; r++) {               // C/D: col=m, row=quad*4+r
            int n = n0 + w * 16 + quad * 4 + r;
            if (n < N_NODES)
                xl[(size_t)n * HC + jt * 16 + m] = __float2bfloat16(acc[r]);
        }
    }
    __syncthreads();                                // all waves done with Ws

    for (int i = t; i < DIN * HC / 4; i += 256) {
        const float4 wv = ((const float4*)Wr)[i];
        const int c = i >> 5, j = (i & 31) * 4;
        Ws[j][c]     = f2bf(wv.x);
        Ws[j + 1][c] = f2bf(wv.y);
        Ws[j + 2][c] = f2bf(wv.z);
        Ws[j + 3][c] = f2bf(wv.w);
    }
    __syncthreads();

    #pragma unroll
    for (int jt = 0; jt < 8; jt++) {
        floatx4 acc = {0.f, 0.f, 0.f, 0.f};
        #pragma unroll
        for (int kk = 0; kk < 4; kk++) {
            short8 bfr = *(const short8*)&Ws[jt * 16 + m][kk * 32 + quad * 8];
            acc = __builtin_amdgcn_mfma_f32_16x16x32_bf16(af[kk], bfr, acc, 0, 0, 0);
        }
        #pragma unroll
        for (int r = 0; r < 4; r++) {
            int n = n0 + w * 16 + quad * 4 + r;
            if (n < N_NODES)
                xr[(size_t)n * HC + jt * 16 + m] = __float2bfloat16(acc[r]);
        }
    }
}

// In-degree count.
__global__ __launch_bounds__(256) void k_count(
    const int* __restrict__ ei, unsigned* __restrict__ deg)
{
    const int e = blockIdx.x * 256 + threadIdx.x;   // grid == E exactly
    atomicAdd(&deg[ei[N_EDGES + e]], 1u);
}

// Scan stage 1: block-local exclusive scan + per-block sums.
__global__ __launch_bounds__(SCAN_B) void k_scan1(
    const unsigned* __restrict__ deg, unsigned* __restrict__ offs,
    unsigned* __restrict__ bsum)
{
    __shared__ unsigned sh[SCAN_B];
    const int t = threadIdx.x, i = blockIdx.x * SCAN_B + t;
    const unsigned d = (i < N_NODES) ? deg[i] : 0u;
    sh[t] = d;
    __syncthreads();
    for (int off = 1; off < SCAN_B; off <<= 1) {
        unsigned v = (t >= off) ? sh[t - off] : 0u;
        __syncthreads();
        sh[t] += v;
        __syncthreads();
    }
    if (i < N_NODES) offs[i] = sh[t] - d;           // block-local exclusive
    if (t == SCAN_B - 1) bsum[blockIdx.x] = sh[t];
}

// Scan stage 2+3 (blocks 0..195) + cvec = bias@Wp + bp (block 196).
__global__ __launch_bounds__(SCAN_B) void k_scan23(
    unsigned* __restrict__ offs, const unsigned* __restrict__ bsum,
    unsigned* __restrict__ cursor,
    const float* __restrict__ bias, const float* __restrict__ Wp,
    const float* __restrict__ bp, float* __restrict__ cvec)
{
    const int t = threadIdx.x, b = blockIdx.x;
    if (b == SCAN_NB) {
        if (t < DOUT) {
            float v = bp[t];
            for (int c = 0; c < HC; c++) v += bias[c] * Wp[c * DOUT + t];
            cvec[t] = v;
        }
        return;
    }
    __shared__ unsigned red[SCAN_B];
    red[t] = (t < SCAN_NB && t < b) ? bsum[t] : 0u;
    __syncthreads();
    for (int off = SCAN_B / 2; off > 0; off >>= 1) {
        if (t < off) red[t] += red[t + off];
        __syncthreads();
    }
    const unsigned base = red[0];
    const int i = b * SCAN_B + t;
    if (i < N_NODES) {
        const unsigned v = offs[i] + base;
        offs[i] = v;
        cursor[i] = v;
    }
    if (i == 0) offs[N_NODES] = N_EDGES;
}

// Bucket src ids by dst.
__global__ __launch_bounds__(256) void k_fill(
    const int* __restrict__ ei, unsigned* __restrict__ cursor,
    int* __restrict__ srcs)
{
    const int e = blockIdx.x * 256 + threadIdx.x;   // grid == E exactly
    const int dst = ei[N_EDGES + e];
    const unsigned pos = atomicAdd(&cursor[dst], 1u);
    srcs[pos] = ei[e];
}

// Fused logit + exp + aggregate + projection. One wave per node.
// Lane = (es = lane>>4, hq = lane&15): 4 edge slots x 16 lanes; lane owns
// cols 8hq..8hq+7 (head = hq>>2); head-dot reduce = 2 shuffles over the
// 4-lane group. Two scalar buffers per slot -> 8 rows in flight per wave.
// No dynamically-indexed register arrays (round-8 lesson).
__global__ __launch_bounds__(256) void k_agg(
    const int* __restrict__ srcs, const unsigned* __restrict__ offs,
    const unsigned* __restrict__ xl2,   // bf16 xl as uint pairs [N][64]
    const unsigned* __restrict__ xr2,   // bf16 xr as uint pairs [N][64]
    const float* __restrict__ att,
    const float* __restrict__ Wp, const float* __restrict__ cvec,
    float* __restrict__ out)
{
    __shared__ float sWp[HC][DOUT];     // 16 KB
    __shared__ float srow[4][HC];
    const int t = threadIdx.x;
    for (int i = t; i < HC * DOUT; i += 256)
        ((float*)sWp)[i] = Wp[i];
    __syncthreads();

    const int w = t >> 6, lane = t & 63;
    const int node = blockIdx.x * 4 + w;
    const int es = lane >> 4, hq = lane & 15;
    const int c0 = hq * 8;

    const uint4 xru = ((const uint4*)(xr2 + (size_t)node * 64))[hq];
    float xr_[8];
    xr_[0] = bflo(xru.x); xr_[1] = bfhi(xru.x);
    xr_[2] = bflo(xru.y); xr_[3] = bfhi(xru.y);
    xr_[4] = bflo(xru.z); xr_[5] = bfhi(xru.z);
    xr_[6] = bflo(xru.w); xr_[7] = bfhi(xru.w);
    const float4 av0 = ((const float4*)att)[hq * 2];
    const float4 av1 = ((const float4*)att)[hq * 2 + 1];
    const float a_[8] = {av0.x, av0.y, av0.z, av0.w, av1.x, av1.y, av1.z, av1.w};

    const unsigned lo = offs[node], hi = offs[node + 1];
    float s_run = 0.f;
    float acc[8] = {0.f, 0.f, 0.f, 0.f, 0.f, 0.f, 0.f, 0.f};

    for (unsigned base = lo; base < hi; base += 64) {
        const unsigned j = base + lane;
        const int srcj = (j < hi) ? srcs[j] : 0;
        const int cnt = (int)((hi - base < 64u) ? (hi - base) : 64u);
        // slot es handles edges es, es+4, es+8, ... double-buffered (xa, xb)
        int sj = __shfl(srcj, es, 64);
        uint4 xa = ((const uint4*)(xl2 + ((size_t)((es < cnt) ? sj : 0) << 6)))[hq];
        sj = __shfl(srcj, (es + 4) & 63, 64);
        uint4 xb = ((const uint4*)(xl2 + ((size_t)((es + 4 < cnt) ? sj : 0) << 6)))[hq];
        for (int i = 0; i < cnt; i += 8) {
            #pragma unroll
            for (int u = 0; u < 2; u++) {           // u=0 -> xa, u=1 -> xb
                const int eidx = i + es + 4 * u;
                const uint4 cur = u ? xb : xa;
                const int ii = eidx + 8;
                sj = __shfl(srcj, ii & 63, 64);
                const uint4 nxt = ((const uint4*)(xl2 + ((size_t)((ii < cnt) ? sj : 0) << 6)))[hq];
                if (u) xb = nxt; else xa = nxt;

                float x_[8];
                x_[0] = bflo(cur.x); x_[1] = bfhi(cur.x);
                x_[2] = bflo(cur.y); x_[3] = bfhi(cur.y);
                x_[4] = bflo(cur.z); x_[5] = bfhi(cur.z);
                x_[6] = bflo(cur.w); x_[7] = bfhi(cur.w);
                float p = 0.f;
                #pragma unroll
                for (int k = 0; k < 8; k++) {
                    float v = x_[k] + xr_[k];
                    v = fmaxf(v, NEG_SLOPE * v);
                    p = fmaf(a_[k], v, p);
                }
                p += __shfl_xor(p, 1, 64);
                p += __shfl_xor(p, 2, 64);          // logit(edge eidx, head)
                const float e_ = (eidx < cnt) ? __expf(p) : 0.f;
                s_run += e_;
                #pragma unroll
                for (int k = 0; k < 8; k++) acc[k] = fmaf(x_[k], e_, acc[k]);
            }
        }
    }
    // combine the 4 edge slots (lanes differing in bits 4,5; same cols)
    s_run += __shfl_xor(s_run, 16, 64);
    s_run += __shfl_xor(s_run, 32, 64);
    #pragma unroll
    for (int k = 0; k < 8; k++) {
        acc[k] += __shfl_xor(acc[k], 16, 64);
        acc[k] += __shfl_xor(acc[k], 32, 64);
    }
    const float rden = 1.f / (s_run + 1e-16f);

    if (es == 0) {
        float4 r0 = {acc[0] * rden, acc[1] * rden, acc[2] * rden, acc[3] * rden};
        float4 r1 = {acc[4] * rden, acc[5] * rden, acc[6] * rden, acc[7] * rden};
        *(float4*)&srow[w][c0]     = r0;
        *(float4*)&srow[w][c0 + 4] = r1;
    }
    // same-wave LDS RAW: in-order DS pipe, no barrier needed
    const int jj = lane & 31, half = lane >> 5;
    float pacc = 0.f;
    const int cb = half * 64;
    #pragma unroll 8
    for (int c = 0; c < 64; c++)
        pacc += srow[w][cb + c] * sWp[cb + c][jj];
    pacc += __shfl_down(pacc, 32, 64);
    if (lane < 32)
        out[(size_t)node * DOUT + jj] = pacc + cvec[jj];
}

extern "C" void kernel_launch(void* const* d_in, const int* in_sizes, int n_in,
                              void* d_out, int out_size, void* d_ws, size_t ws_size,
                              hipStream_t stream)
{
    const float* x    = (const float*)d_in[0];
    const int*   ei   = (const int*)d_in[1];
    const float* Wl   = (const float*)d_in[2];
    const float* Wr   = (const float*)d_in[3];
    const float* att  = (const float*)d_in[4];
    const float* bias = (const float*)d_in[5];
    const float* Wp   = (const float*)d_in[6];
    const float* bp   = (const float*)d_in[7];
    float* out = (float*)d_out;

    // workspace (~28.4 MB):
    // xl bf16[N*HC] | xr bf16[N*HC] | cvec f32[32] | deg/cursor u32[N]
    // | offs u32[N+1] | bsum u32[256] | srcs i32[E]
    bf16* xl       = (bf16*)d_ws;
    bf16* xr       = xl + (size_t)N_NODES * HC;
    float* cvec    = (float*)(xr + (size_t)N_NODES * HC);
    unsigned* deg  = (unsigned*)(cvec + DOUT);
    unsigned* offs = deg + N_NODES;
    unsigned* bsum = offs + (N_NODES + 1);
    int* srcs      = (int*)(bsum + 256);

    k_transform<<<TF_NB, 256, 0, stream>>>(x, Wl, Wr, xl, xr, deg);
    k_count<<<N_EDGES / 256, 256, 0, stream>>>(ei, deg);
    k_scan1<<<SCAN_NB, SCAN_B, 0, stream>>>(deg, offs, bsum);
    k_scan23<<<SCAN_NB + 1, SCAN_B, 0, stream>>>(offs, bsum, deg,
                                                 bias, Wp, bp, cvec);
    k_fill<<<N_EDGES / 256, 256, 0, stream>>>(ei, deg, srcs);
    k_agg<<<N_NODES / 4, 256, 0, stream>>>(srcs, offs,
        (const unsigned*)xl, (const unsigned*)xr, att, Wp, cvec, out);
}